// Round 4
// baseline (310.561 us; speedup 1.0000x reference)
//
#include <hip/hip_runtime.h>

// out[b,h,w,c] = sum_j w[j,c] * t_j[b,h,w,c]
// B,H,W,C = 8,128,128,128 -> N = 16,777,216 f32, nvec = 4,194,304 float4.
// Pure HBM-bound elementwise: 320 MiB read + 64 MiB write per call.
//
// History:
//  v1: 1 f4/thread, 16384 blocks          -> 117 us (3.4 TB/s effective)
//  v3: 4x/thread 16MiB strides, NT stores -> 146 us (stride regression; NT null)
//  v4: 8x/thread contiguous 32KiB tiles   -> 124 us (wave-churn theory null)
//  Constants across all: FETCH 164 MB, WRITE 64 MiB, VALUBusy ~1.6%.
//
//  v5 (this file): STREAM-MAJOR ordering with wave-contiguous bursts.
//  Theory: 6 finely-interleaved address streams thrash DRAM row buffers
//  (copy=2 streams hits 6.3 TB/s; RMSNorm~2 hits 4.9; we're stuck at 3.4).
//  Each wave owns a contiguous 8 KiB chunk PER STREAM and walks streams
//  sequentially with an f4 accumulator:
//    8x 1KiB contiguous loads from t1, then t2, ... then one 8KiB store.
//  Per-channel DRAM queues see long same-row runs; concurrent open-region
//  count drops ~6x. MLP preserved (no sched barriers; compiler clusters
//  loads in stream-major source order).

typedef float f4 __attribute__((ext_vector_type(4)));

#define TPB 256
#define KPT 8                       // f4 per thread
#define WAVE_CHUNK (64 * KPT)       // 512 f4 = 8 KiB contiguous per wave per stream
#define BLOCK_CHUNK (TPB * KPT)     // 2048 f4 = 32 KiB per stream per block

__global__ __launch_bounds__(256) void merge5_kernel(
    const float* __restrict__ t1, const float* __restrict__ t2,
    const float* __restrict__ t3, const float* __restrict__ t4,
    const float* __restrict__ t5, const float* __restrict__ w,
    float* __restrict__ out, int nvec)
{
    int tid  = threadIdx.x;
    int lane = tid & 63;
    int wave = tid >> 6;

    // Wave-contiguous base: wave owns [base, base + 512) f4, thread handles
    // base + k*64 + lane for k = 0..7. k*64 keeps (i & 31) == (lane & 31),
    // so the weight vectors are invariant across all 8 elements.
    int base = blockIdx.x * BLOCK_CHUNK + wave * WAVE_CHUNK + lane;

    int c4 = (lane & 31) << 2;
    const f4 w0 = *(const f4*)(w + 0 * 128 + c4);
    const f4 w1 = *(const f4*)(w + 1 * 128 + c4);
    const f4 w2 = *(const f4*)(w + 2 * 128 + c4);
    const f4 w3 = *(const f4*)(w + 3 * 128 + c4);
    const f4 w4 = *(const f4*)(w + 4 * 128 + c4);

    const f4* p1 = (const f4*)t1;
    const f4* p2 = (const f4*)t2;
    const f4* p3 = (const f4*)t3;
    const f4* p4 = (const f4*)t4;
    const f4* p5 = (const f4*)t5;
    f4* po = (f4*)out;

    f4 acc[KPT];

    if (base + (KPT - 1) * 64 < nvec) {
        // Fast path (always taken for the bench shape).
        // Stream-major: all 8 contiguous loads of one stream issue
        // back-to-back before the next stream's loads.
#pragma unroll
        for (int k = 0; k < KPT; ++k) acc[k] = p1[base + k * 64] * w0;
#pragma unroll
        for (int k = 0; k < KPT; ++k) acc[k] += p2[base + k * 64] * w1;
#pragma unroll
        for (int k = 0; k < KPT; ++k) acc[k] += p3[base + k * 64] * w2;
#pragma unroll
        for (int k = 0; k < KPT; ++k) acc[k] += p4[base + k * 64] * w3;
#pragma unroll
        for (int k = 0; k < KPT; ++k) acc[k] += p5[base + k * 64] * w4;
#pragma unroll
        for (int k = 0; k < KPT; ++k) po[base + k * 64] = acc[k];
    } else {
        // Tail path (not taken for the bench shape).
        for (int k = 0; k < KPT; ++k) {
            int i = base + k * 64;
            if (i < nvec) {
                f4 a = p1[i], b = p2[i], c = p3[i], d = p4[i], e = p5[i];
                po[i] = a * w0 + b * w1 + c * w2 + d * w3 + e * w4;
            }
        }
    }
}

extern "C" void kernel_launch(void* const* d_in, const int* in_sizes, int n_in,
                              void* d_out, int out_size, void* d_ws, size_t ws_size,
                              hipStream_t stream) {
    const float* t1 = (const float*)d_in[0];
    const float* t2 = (const float*)d_in[1];
    const float* t3 = (const float*)d_in[2];
    const float* t4 = (const float*)d_in[3];
    const float* t5 = (const float*)d_in[4];
    const float* w  = (const float*)d_in[5];
    float* out = (float*)d_out;

    int nvec = out_size / 4;                          // 4,194,304 f4
    int blocks = (nvec + BLOCK_CHUNK - 1) / BLOCK_CHUNK;  // 2048

    merge5_kernel<<<blocks, TPB, 0, stream>>>(t1, t2, t3, t4, t5, w, out, nvec);
}

// Round 5
// 303.892 us; speedup vs baseline: 1.0219x; 1.0219x over previous
//
#include <hip/hip_runtime.h>

// out[b,h,w,c] = sum_j w[j,c] * t_j[b,h,w,c]
// B,H,W,C = 8,128,128,128 -> N = 16,777,216 f32, nvec = 4,194,304 float4.
// Pure HBM-bound elementwise: 320 MiB read + 64 MiB write per call.
//
// History (dispatch dur from rocprof):
//  v1: 1 f4/thread, 16384 blocks            -> 117 us (best), VGPR 28
//  v3: 4x/thread 16MiB strides + NT stores  -> 146 us (strides hurt; NT null)
//  v4: 8x/thread contiguous 32KiB tiles     -> 124 us (wave-churn theory null)
//  v5: stream-major wave-chunk ordering     -> 125 us (stream-mix theory null)
//  Constants: FETCH 164 MB, WRITE 64 MiB, VALUBusy ~1.6%, 0 bank conflicts.
//
//  KEY post-mortem finding: v3/v5 reported VGPR=36/40 -- the compiler SANK
//  every load next to its use, so per-wave MLP stayed ~5 outstanding loads
//  in ALL versions. The deep-MLP hypothesis was never actually tested.
//
//  v6: force 20 tensor loads in flight before any FMA via
//  __builtin_amdgcn_sched_barrier(0) between load block and compute block.
//  Wave-contiguous 4 KiB chunks per stream (no giant strides). KPT=4.
//  Expect VGPR ~110 (the landing check), occupancy ~50%, and -- if the
//  latency/MLP theory is right -- dur 117 -> 75..95 us.

typedef float f4 __attribute__((ext_vector_type(4)));

#define TPB 256
#define KPT 4                        // f4 per thread
#define WAVE_CHUNK (64 * KPT)        // 256 f4 = 4 KiB contiguous per wave/stream
#define BLOCK_CHUNK (TPB * KPT)      // 1024 f4 = 16 KiB per stream per block

__global__ __launch_bounds__(256) void merge5_kernel(
    const float* __restrict__ t1, const float* __restrict__ t2,
    const float* __restrict__ t3, const float* __restrict__ t4,
    const float* __restrict__ t5, const float* __restrict__ w,
    float* __restrict__ out, int nvec)
{
    int tid  = threadIdx.x;
    int lane = tid & 63;
    int wave = tid >> 6;

    // Wave owns [base, base+256) f4 per stream; thread handles base + k*64.
    // k*64 / wave*256 / blk*1024 are multiples of 32 -> (i & 31) == (lane & 31),
    // so the weight vectors are invariant across all 4 elements.
    int base = blockIdx.x * BLOCK_CHUNK + wave * WAVE_CHUNK + lane;

    int c4 = (lane & 31) << 2;
    const f4 w0 = *(const f4*)(w + 0 * 128 + c4);
    const f4 w1 = *(const f4*)(w + 1 * 128 + c4);
    const f4 w2 = *(const f4*)(w + 2 * 128 + c4);
    const f4 w3 = *(const f4*)(w + 3 * 128 + c4);
    const f4 w4 = *(const f4*)(w + 4 * 128 + c4);

    const f4* p1 = (const f4*)t1;
    const f4* p2 = (const f4*)t2;
    const f4* p3 = (const f4*)t3;
    const f4* p4 = (const f4*)t4;
    const f4* p5 = (const f4*)t5;
    f4* po = (f4*)out;

    int i0 = base, i1 = base + 64, i2 = base + 128, i3 = base + 192;

    if (i3 < nvec) {
        // ---- load block: all 20 loads issued, none may sink past the barrier
        f4 a0 = p1[i0], a1 = p1[i1], a2 = p1[i2], a3 = p1[i3];
        f4 b0 = p2[i0], b1 = p2[i1], b2 = p2[i2], b3 = p2[i3];
        f4 c0 = p3[i0], c1 = p3[i1], c2 = p3[i2], c3 = p3[i3];
        f4 d0 = p4[i0], d1 = p4[i1], d2 = p4[i2], d3 = p4[i3];
        f4 e0 = p5[i0], e1 = p5[i1], e2 = p5[i2], e3 = p5[i3];

        __builtin_amdgcn_sched_barrier(0);   // no motion across: forces MLP

        // ---- compute + store block (consumes in load-completion order)
        f4 r0 = a0 * w0 + b0 * w1 + c0 * w2 + d0 * w3 + e0 * w4;
        f4 r1 = a1 * w0 + b1 * w1 + c1 * w2 + d1 * w3 + e1 * w4;
        f4 r2 = a2 * w0 + b2 * w1 + c2 * w2 + d2 * w3 + e2 * w4;
        f4 r3 = a3 * w0 + b3 * w1 + c3 * w2 + d3 * w3 + e3 * w4;

        po[i0] = r0;
        po[i1] = r1;
        po[i2] = r2;
        po[i3] = r3;
    } else {
        // Tail path (not taken for the bench shape).
        for (int k = 0; k < KPT; ++k) {
            int i = base + k * 64;
            if (i < nvec) {
                f4 a = p1[i], b = p2[i], c = p3[i], d = p4[i], e = p5[i];
                po[i] = a * w0 + b * w1 + c * w2 + d * w3 + e * w4;
            }
        }
    }
}

extern "C" void kernel_launch(void* const* d_in, const int* in_sizes, int n_in,
                              void* d_out, int out_size, void* d_ws, size_t ws_size,
                              hipStream_t stream) {
    const float* t1 = (const float*)d_in[0];
    const float* t2 = (const float*)d_in[1];
    const float* t3 = (const float*)d_in[2];
    const float* t4 = (const float*)d_in[3];
    const float* t5 = (const float*)d_in[4];
    const float* w  = (const float*)d_in[5];
    float* out = (float*)d_out;

    int nvec = out_size / 4;                             // 4,194,304 f4
    int blocks = (nvec + BLOCK_CHUNK - 1) / BLOCK_CHUNK; // 4096

    merge5_kernel<<<blocks, TPB, 0, stream>>>(t1, t2, t3, t4, t5, w, out, nvec);
}

// Round 6
// 288.591 us; speedup vs baseline: 1.0761x; 1.0530x over previous
//
#include <hip/hip_runtime.h>

// out[b,h,w,c] = sum_j w[j,c] * t_j[b,h,w,c]
// B,H,W,C = 8,128,128,128 -> N = 16,777,216 f32, nvec = 4,194,304 float4.
// Pure HBM-bound elementwise: 320 MiB read + 64 MiB write per call.
//
// History (per-dispatch dur from rocprof):
//  v1: 1 f4/thread, 16384 blocks            -> 117 us (best), VGPR 28, occ 72%
//  v3: 4x/thread 16MiB strides + NT stores  -> 146 us (strides hurt; NT-store null)
//  v4: 8x/thread contiguous 32KiB tiles     -> 124 us (wave-churn null)
//  v5: stream-major wave-chunk ordering     -> 125 us (stream-mix null)
//  v6: sched_barrier forced-MLP             -> VOID (VGPR 56, not 110; ~115 us)
//  Constants: FETCH 164 MB, WRITE 64 MiB, VALUBusy ~1.5%, 0 conflicts.
//
//  Analysis: offered in-flight bytes (~115 KiB/CU) >> BDP (~25 KiB/CU), yet
//  aggregate serve rate pins at 3.44 TB/s across five structurally different
//  kernels -> capacity limit in the L2/fabric/MALL/HBM complex, split as
//  ~2.0 TB/s HBM-path + ~1.5 TB/s LLC-hit-path.
//
//  v7 (this file): NON-TEMPORAL LOADS on the 5 tensor streams (NT *loads*
//  were never tested; v3 tested NT stores). Theory: the MALL-hit serve path
//  is the co-limiter at ~1.5 TB/s; streaming reads past the LLC serves all
//  337 MB of reads from HBM, which has ~4 TB/s headroom.
//  Landing check: FETCH_SIZE must jump 164 MB -> ~330 MB, else void.
//  Win branch: 117 -> 75-95 us. Lose branch: ~150-180 us, proving the LLC
//  assist is load-bearing -> revert to v1 and declare roofline.
//  Structure otherwise identical to v1 (the best kernel).

typedef float f4 __attribute__((ext_vector_type(4)));

__global__ __launch_bounds__(256) void merge5_kernel(
    const float* __restrict__ t1, const float* __restrict__ t2,
    const float* __restrict__ t3, const float* __restrict__ t4,
    const float* __restrict__ t5, const float* __restrict__ w,
    float* __restrict__ out, int nvec)
{
    int idx = blockIdx.x * 256 + threadIdx.x;
    if (idx >= nvec) return;

    // channel base for this float4 (C=128 -> 32 float4s per channel period)
    int c4 = (idx & 31) << 2;

    // weights: plain loads (128 B x5 total, heavily reused, L2-hot)
    const f4 w0 = *(const f4*)(w + 0 * 128 + c4);
    const f4 w1 = *(const f4*)(w + 1 * 128 + c4);
    const f4 w2 = *(const f4*)(w + 2 * 128 + c4);
    const f4 w3 = *(const f4*)(w + 3 * 128 + c4);
    const f4 w4 = *(const f4*)(w + 4 * 128 + c4);

    const f4* p1 = (const f4*)t1;
    const f4* p2 = (const f4*)t2;
    const f4* p3 = (const f4*)t3;
    const f4* p4 = (const f4*)t4;
    const f4* p5 = (const f4*)t5;
    f4* po = (f4*)out;

    // tensor streams: non-temporal loads (single-use, bypass/stream LLC)
    f4 a = __builtin_nontemporal_load(p1 + idx);
    f4 b = __builtin_nontemporal_load(p2 + idx);
    f4 c = __builtin_nontemporal_load(p3 + idx);
    f4 d = __builtin_nontemporal_load(p4 + idx);
    f4 e = __builtin_nontemporal_load(p5 + idx);

    f4 r = a * w0 + b * w1 + c * w2 + d * w3 + e * w4;

    po[idx] = r;   // plain store (NT store measured null in v3)
}

extern "C" void kernel_launch(void* const* d_in, const int* in_sizes, int n_in,
                              void* d_out, int out_size, void* d_ws, size_t ws_size,
                              hipStream_t stream) {
    const float* t1 = (const float*)d_in[0];
    const float* t2 = (const float*)d_in[1];
    const float* t3 = (const float*)d_in[2];
    const float* t4 = (const float*)d_in[3];
    const float* t5 = (const float*)d_in[4];
    const float* w  = (const float*)d_in[5];
    float* out = (float*)d_out;

    int nvec = out_size / 4;           // 4,194,304 float4s
    int blocks = (nvec + 255) / 256;   // 16384

    merge5_kernel<<<blocks, 256, 0, stream>>>(t1, t2, t3, t4, t5, w, out, nvec);
}

// Round 7
// 287.539 us; speedup vs baseline: 1.0801x; 1.0037x over previous
//
#include <hip/hip_runtime.h>

// out[b,h,w,c] = sum_j w[j,c] * t_j[b,h,w,c]
// B,H,W,C = 8,128,128,128 -> N = 16,777,216 f32, nvec = 4,194,304 float4.
// Pure HBM-bound elementwise: 320 MiB read + 64 MiB write per call.
//
// History (per-dispatch dur from rocprof):
//  v1: 1 f4/thread, 16384 blocks            -> 117 us, VGPR 28, occ 72%
//  v3: 4x/thread 16MiB strides + NT stores  -> 146 us (strides hurt; bundled)
//  v4: 8x/thread contiguous 32KiB tiles     -> 124 us (wave-churn null)
//  v5: stream-major wave-chunk ordering     -> 125 us (stream-mix null)
//  v6: sched_barrier forced-MLP             -> VOID (VGPR 56, not 110)
//  v7: NT LOADS on the 5 tensor streams     -> 74 us (1.58x WIN)
//      FETCH unchanged (164 MB) -> mechanism is cache *policy* (L1 bypass +
//      L2 streaming allocation), not traffic reduction. Effective logical BW
//      402.6 MB / 74 us = 5.44 TB/s = 86% of the 6.3 TB/s copy ceiling.
//
//  v8 (this file): single change vs v7 -- NT STORES on the output stream.
//  (v3's NT-store datapoint was bundled with a bad stride layout; untested
//  as an isolated change on the winning structure.) Theory: the 64 MiB
//  output still write-allocates into L2 with MRU policy; `nt` removes the
//  allocate/promotion overhead like it did for reads.
//  Predictions: FETCH/WRITE unchanged; win 74 -> 66-71 us; null 73-75 us
//  (then declare roofline); >80 us -> revert to v7 + roofline.

typedef float f4 __attribute__((ext_vector_type(4)));

__global__ __launch_bounds__(256) void merge5_kernel(
    const float* __restrict__ t1, const float* __restrict__ t2,
    const float* __restrict__ t3, const float* __restrict__ t4,
    const float* __restrict__ t5, const float* __restrict__ w,
    float* __restrict__ out, int nvec)
{
    int idx = blockIdx.x * 256 + threadIdx.x;
    if (idx >= nvec) return;

    // channel base for this float4 (C=128 -> 32 float4s per channel period)
    int c4 = (idx & 31) << 2;

    // weights: plain loads (640 B total, heavily reused, cache-hot)
    const f4 w0 = *(const f4*)(w + 0 * 128 + c4);
    const f4 w1 = *(const f4*)(w + 1 * 128 + c4);
    const f4 w2 = *(const f4*)(w + 2 * 128 + c4);
    const f4 w3 = *(const f4*)(w + 3 * 128 + c4);
    const f4 w4 = *(const f4*)(w + 4 * 128 + c4);

    const f4* p1 = (const f4*)t1;
    const f4* p2 = (const f4*)t2;
    const f4* p3 = (const f4*)t3;
    const f4* p4 = (const f4*)t4;
    const f4* p5 = (const f4*)t5;
    f4* po = (f4*)out;

    // tensor streams: non-temporal loads (single-use; L1 bypass + L2 stream)
    f4 a = __builtin_nontemporal_load(p1 + idx);
    f4 b = __builtin_nontemporal_load(p2 + idx);
    f4 c = __builtin_nontemporal_load(p3 + idx);
    f4 d = __builtin_nontemporal_load(p4 + idx);
    f4 e = __builtin_nontemporal_load(p5 + idx);

    f4 r = a * w0 + b * w1 + c * w2 + d * w3 + e * w4;

    // output: non-temporal store (write-once, never re-read)
    __builtin_nontemporal_store(r, po + idx);
}

extern "C" void kernel_launch(void* const* d_in, const int* in_sizes, int n_in,
                              void* d_out, int out_size, void* d_ws, size_t ws_size,
                              hipStream_t stream) {
    const float* t1 = (const float*)d_in[0];
    const float* t2 = (const float*)d_in[1];
    const float* t3 = (const float*)d_in[2];
    const float* t4 = (const float*)d_in[3];
    const float* t5 = (const float*)d_in[4];
    const float* w  = (const float*)d_in[5];
    float* out = (float*)d_out;

    int nvec = out_size / 4;           // 4,194,304 float4s
    int blocks = (nvec + 255) / 256;   // 16384

    merge5_kernel<<<blocks, 256, 0, stream>>>(t1, t2, t3, t4, t5, w, out, nvec);
}